// Round 6
// baseline (167.444 us; speedup 1.0000x reference)
//
#include <hip/hip_runtime.h>

#define NB 8732
#define NC 21
#define BATCH 128
#define BX 35   // ceil(8732/256)

// ws layout (dwords):
//   [0 .. 17920)        block partial slots: (r*BX+bx)*4 = two packed u64 {ce|pce, loc|np}
//   [17920 .. 18432)    row results: WS_ROW + r*4 = two packed u64 {rowval|loc_row, np|0}
//   [18432 .. 22560)    tickets, one per 128-B line: rowcnt[r] at WS_CNT+r*32, done at WS_CNT+BATCH*32
//   [22560 .. )         cold-path key arrays: WS_KEY + r*NB  (global radix scratch)
#define WS_ROW (BATCH * BX * 4)
#define WS_CNT (WS_ROW + BATCH * 4)
#define WS_KEY (WS_CNT + (BATCH + 1) * 32)

typedef float v4f __attribute__((ext_vector_type(4)));
typedef unsigned long long u64;

__device__ inline float wred_f(float v) {
#pragma unroll
    for (int o = 32; o > 0; o >>= 1) v += __shfl_down(v, o, 64);
    return v;
}

__device__ inline u64 packf2(float a, float b) {
    return (u64)__float_as_uint(a) | ((u64)__float_as_uint(b) << 32);
}
__device__ inline float lo_f(u64 u) { return __uint_as_float((unsigned)u); }
__device__ inline float hi_f(u64 u) { return __uint_as_float((unsigned)(u >> 32)); }

// r12: conf staging via global_load_lds (TA->LDS DMA, 16B/lane). Bypasses the
// VGPR/L1 line-fill return path that caps VGPR loads at ~4.5 B/cyc/CU (kF was
// 46us = 3.0 TB/s; fills do 6.7 TB/s write-only on the same CUs). LDS dest is
// wave-uniform base + lane*16 (m104) -- our layout is already exactly linear.
__device__ inline void gl_lds16(const v4f* __restrict__ g, v4f* l) {
    __builtin_amdgcn_global_load_lds(
        (const __attribute__((address_space(1))) void*)g,
        (__attribute__((address_space(3))) void*)l,
        16, 0, 0);
}

__device__ inline float ce_for_box0(const float* __restrict__ cp) {
    float c[NC];
#pragma unroll
    for (int j = 0; j < NC; j++) c[j] = cp[j];
    float m = c[0];
#pragma unroll
    for (int j = 1; j < NC; j++) m = fmaxf(m, c[j]);
    float s = 0.f;
#pragma unroll
    for (int j = 0; j < NC; j++) s += __expf(c[j] - m);
    return m + __logf(s) - c[0];
}

// Fused last-block-done kernel (r11 structure, fence-free, 64-bit atomic
// publishes, line-padded tickets). Reduction trees identical -> bit-identical.
__global__ void __launch_bounds__(256)
kF(const float* __restrict__ locp, const float* __restrict__ loct,
   const float* __restrict__ conf, const int* __restrict__ lab,
   float* __restrict__ ws, float* __restrict__ out) {
    __shared__ v4f xb4[4][336];   // 21504 B; total LDS ~22.7 KB -> 7 blocks/CU
    unsigned* wsu = (unsigned*)ws;
    const int r = blockIdx.y;
    const int w = threadIdx.x >> 6;
    const int ln = threadIdx.x & 63;
    const int box0 = blockIdx.x * 256 + w * 64;

    float ceS = 0.f, pceS = 0.f, llS = 0.f, npS = 0.f;

    if (box0 < NB) {
        const int cnt = min(64, NB - box0);
        const size_t rowbase = (size_t)r * NB;
        const float* __restrict__ src = conf + (rowbase + box0) * (size_t)NC;
        const v4f* __restrict__ s4 = (const v4f*)src;   // 16-B aligned: (8732*84)%16==0, (64*84)%16==0

        // side loads issued first (oldest in queue), in flight during staging
        int l = 0;
        v4f lp = {0.f, 0.f, 0.f, 0.f}, lt = {0.f, 0.f, 0.f, 0.f};
        if (ln < cnt) {
            const size_t box = rowbase + box0 + ln;
            l = __builtin_nontemporal_load(lab + box);
            lp = __builtin_nontemporal_load((const v4f*)(locp + box * 4));
            lt = __builtin_nontemporal_load((const v4f*)(loct + box * 4));
        }

        // conf staging: LDS-DMA, 1344 floats = 336 vec4 = 5 full waves + 16
        if (cnt == 64) {
#pragma unroll
            for (int k = 0; k < 5; k++)
                gl_lds16(s4 + (k << 6) + ln, &xb4[w][k << 6]);
            if (ln < 16)
                gl_lds16(s4 + 320 + ln, &xb4[w][320]);
        } else {
            // only tail is cnt=28: 588 floats = exactly 147 vec4
            const int n4 = (cnt * NC) >> 2;
#pragma unroll
            for (int k = 0; k < 6; k++) {
                const int i4 = (k << 6) + ln;
                if (i4 < n4) gl_lds16(s4 + i4, &xb4[w][k << 6]);
            }
        }
        // global_load_lds completion is tracked by vmcnt; wave-local use -> no barrier
        asm volatile("s_waitcnt vmcnt(0)" ::: "memory");
        __builtin_amdgcn_sched_barrier(0);

        if (ln < cnt) {
            float c[NC];
            const float* bp = (const float*)&xb4[w][0] + NC * ln;
#pragma unroll
            for (int j = 0; j < NC; j++) c[j] = bp[j];
            float m = c[0];
#pragma unroll
            for (int j = 1; j < NC; j++) m = fmaxf(m, c[j]);
            float s = 0.f;
#pragma unroll
            for (int j = 0; j < NC; j++) s += __expf(c[j] - m);
            float gold = c[0];
#pragma unroll
            for (int j = 1; j < NC; j++) gold = (j == l) ? c[j] : gold;
            const float ce = m + __logf(s) - gold;
            ceS = ce;
            if (l > 0) {
                npS = 1.f;
                pceS = ce;
                float d, ad;
                d = lp.x - lt.x; ad = fabsf(d); llS += (ad < 1.f) ? 0.5f * d * d : ad - 0.5f;
                d = lp.y - lt.y; ad = fabsf(d); llS += (ad < 1.f) ? 0.5f * d * d : ad - 0.5f;
                d = lp.z - lt.z; ad = fabsf(d); llS += (ad < 1.f) ? 0.5f * d * d : ad - 0.5f;
                d = lp.w - lt.w; ad = fabsf(d); llS += (ad < 1.f) ? 0.5f * d * d : ad - 0.5f;
            }
        }
    }

    __shared__ float sr[4][4];
    __shared__ int s_last;
    float v0 = wred_f(ceS), v1 = wred_f(pceS), v2 = wred_f(llS), v3 = wred_f(npS);
    if (ln == 0) { sr[0][w] = v0; sr[1][w] = v1; sr[2][w] = v2; sr[3][w] = v3; }
    __syncthreads();
    if (threadIdx.x == 0) {
        float A = 0, B = 0, C = 0, D = 0;
#pragma unroll
        for (int k = 0; k < 4; k++) { A += sr[0][k]; B += sr[1][k]; C += sr[2][k]; D += sr[3][k]; }
        u64* slot = (u64*)(wsu + ((size_t)r * BX + blockIdx.x) * 4);
        atomicExch(slot + 0, packf2(A, B));
        atomicExch(slot + 1, packf2(C, D));
        // completion wait: RMWs ACKed by the coherence point before the ticket
        asm volatile("s_waitcnt vmcnt(0)" ::: "memory");
        const unsigned old = atomicAdd(wsu + WS_CNT + (size_t)r * 32, 1u);
        s_last = ((old % BX) == BX - 1);
    }
    __syncthreads();
    if (!s_last) return;

    // ---------------- row finish (old kB), exact same reduction tree ----------------
    __shared__ float srow[4];
    if (threadIdx.x < 64) {
        float a = 0, b = 0, c = 0, d = 0;
        if (threadIdx.x < BX) {
            u64* p = (u64*)(wsu + ((size_t)r * BX + threadIdx.x) * 4);
            const u64 u0 = atomicAdd(p + 0, 0ULL);
            const u64 u1 = atomicAdd(p + 1, 0ULL);
            a = lo_f(u0); b = hi_f(u0); c = lo_f(u1); d = hi_f(u1);
        }
        a = wred_f(a); b = wred_f(b); c = wred_f(c); d = wred_f(d);
        if (threadIdx.x == 0) { srow[0] = a; srow[1] = b; srow[2] = c; srow[3] = d; }
    }
    __syncthreads();
    const float row_ce = srow[0], row_pce = srow[1], row_ll = srow[2];
    const int np = (int)srow[3];
    const int K = min(3 * np, NB - 1);
    const int nneg = NB - np;

    float rowval;
    if (K >= nneg) {
        rowval = row_ce;                       // hot path on this data (np ~ 8316)
    } else if (K <= 0) {
        rowval = row_pce;
    } else {
        // cold path: exact top-K radix select; same-block scratch, plain ops OK
        unsigned* kw = wsu + WS_KEY + (size_t)r * NB;
        __shared__ unsigned hist[256];
        __shared__ unsigned sb[2];
        for (int i = threadIdx.x; i < NB; i += 256) {
            const size_t box = (size_t)r * NB + i;
            unsigned k = 0u;
            if (lab[box] == 0) {
                float ce = ce_for_box0(conf + box * (size_t)NC);
                k = __float_as_uint(fmaxf(ce, 0.f));
            }
            kw[i] = k;
        }
        __syncthreads();
        unsigned prefix = 0;
        int Kr = K;
        for (int round = 3; round >= 0; --round) {
            const int sh = round * 8;
            const unsigned pmask = (round == 3) ? 0u : (0xFFFFFFFFu << (8 * (round + 1)));
            for (int b = threadIdx.x; b < 256; b += 256) hist[b] = 0;
            __syncthreads();
            for (int i = threadIdx.x; i < NB; i += 256) {
                const unsigned k = kw[i];
                if ((k & pmask) == prefix) atomicAdd(&hist[(k >> sh) & 255u], 1u);
            }
            __syncthreads();
            if (threadIdx.x == 0) {
                unsigned cum = 0; int b = 255;
                for (; b > 0; --b) {
                    const unsigned h = hist[b];
                    if (cum + h >= (unsigned)Kr) break;
                    cum += h;
                }
                sb[0] = cum; sb[1] = (unsigned)b;
            }
            __syncthreads();
            Kr -= (int)sb[0];
            prefix |= (sb[1] << sh);
            __syncthreads();
        }
        float local = 0.f;
        for (int i = threadIdx.x; i < NB; i += 256) {
            const unsigned k = kw[i];
            if (k > prefix) local += __uint_as_float(k);
        }
        __shared__ float sred[4];
        float vv = wred_f(local);
        const int ww = threadIdx.x >> 6, lnn = threadIdx.x & 63;
        if (lnn == 0) sred[ww] = vv;
        __syncthreads();
        rowval = row_pce + sred[0] + sred[1] + sred[2] + sred[3]
               + (float)Kr * __uint_as_float(prefix);
    }

    __shared__ int s_done;
    if (threadIdx.x == 0) {
        u64* o = (u64*)(wsu + WS_ROW + r * 4);
        atomicExch(o + 0, packf2(rowval, row_ll));
        atomicExch(o + 1, packf2(srow[3], 0.f));
        asm volatile("s_waitcnt vmcnt(0)" ::: "memory");
        const unsigned old = atomicAdd(wsu + WS_CNT + (size_t)BATCH * 32, 1u);
        s_done = ((old % BATCH) == BATCH - 1);
    }
    __syncthreads();
    if (!s_done) return;

    // ---------------- final reduce (old kC), exact same tree ----------------
    float cf = 0.f, lc = 0.f, nm = 0.f;
    if (threadIdx.x < BATCH) {
        u64* o = (u64*)(wsu + WS_ROW + threadIdx.x * 4);
        const u64 u0 = atomicAdd(o + 0, 0ULL);
        const u64 u1 = atomicAdd(o + 1, 0ULL);
        cf = lo_f(u0); lc = hi_f(u0); nm = lo_f(u1);
    }
    __shared__ float sf[4], sl[4], sn[4];
    float vc = wred_f(cf), vl = wred_f(lc), vn = wred_f(nm);
    if (ln == 0) { sf[w] = vc; sl[w] = vl; sn[w] = vn; }
    __syncthreads();
    if (threadIdx.x == 0) {
        const float CF = sf[0] + sf[1] + sf[2] + sf[3];
        const float LC = sl[0] + sl[1] + sl[2] + sl[3];
        const float NM = sn[0] + sn[1] + sn[2] + sn[3];
        out[0] = (LC + CF) / fmaxf(NM, 1.f);
    }
}

// zero the 129 line-padded ticket counters (ws is poisoned each iteration)
__global__ void __launch_bounds__(256)
kI(unsigned* __restrict__ cnt) {
    if (threadIdx.x < BATCH + 1) cnt[(size_t)threadIdx.x * 32] = 0u;
}

extern "C" void kernel_launch(void* const* d_in, const int* in_sizes, int n_in,
                              void* d_out, int out_size, void* d_ws, size_t ws_size,
                              hipStream_t stream) {
    const float* locp = (const float*)d_in[0];
    const float* loct = (const float*)d_in[1];
    const float* conf = (const float*)d_in[2];
    const int* lab = (const int*)d_in[3];
    float* out = (float*)d_out;
    float* ws = (float*)d_ws;

    hipLaunchKernelGGL(kI, dim3(1), dim3(256), 0, stream, (unsigned*)ws + WS_CNT);
    hipLaunchKernelGGL(kF, dim3(BX, BATCH), dim3(256), 0, stream,
                       locp, loct, conf, lab, ws, out);
}

// Round 7
// 161.063 us; speedup vs baseline: 1.0396x; 1.0396x over previous
//
#include <hip/hip_runtime.h>

#define NB 8732
#define NC 21
#define BATCH 128
#define BX 35   // ceil(8732/256)

// ws layout (dwords), ALL slots written before read -> no zero-init, no memset:
//   [ (r*35+bx)*4 + {0,1,2,3} ] = block partials {ce, pce, loc, np(float)}
//   [ WS_ROW + r*4 + {0,1,2} ]  = per-row {conf_rowval, loc_row, np_row}
#define WS_ROW (BATCH * BX * 4)

typedef float v4f __attribute__((ext_vector_type(4)));

__device__ inline float wred_f(float v) {
#pragma unroll
    for (int o = 32; o > 0; o >>= 1) v += __shfl_down(v, o, 64);
    return v;
}

// r13 = r1 restore (best measured: 162.70 us). Session conclusion: kA is at
// the machine's effective READ roofline (~3.05 TB/s; 137 MB -> ~45 us).
// Evidence: 4 independent staging mechanisms (plain, NT, dwordx4, LDS-DMA)
// all ~45-50 us; harness copyBuffer reads at the same rate; only write-only
// fill reaches 6.7 TB/s. Fusion (r11/r12) null: graph gaps ~= cross-XCD
// atomic-read cost of the fused finisher. Timed region = copy(56) + fill(56)
// + kernels(~50).
__global__ void __launch_bounds__(256)
kA(const float* __restrict__ locp, const float* __restrict__ loct,
   const float* __restrict__ conf, const int* __restrict__ lab,
   float* __restrict__ ws) {
    __shared__ v4f xb4[4][336];   // 4 waves x 1344 floats (21504 B, 7 blocks/CU)
    const int r = blockIdx.y;
    const int w = threadIdx.x >> 6;
    const int ln = threadIdx.x & 63;
    const int box0 = blockIdx.x * 256 + w * 64;

    float ceS = 0.f, pceS = 0.f, llS = 0.f, npS = 0.f;

    if (box0 < NB) {
        const int cnt = min(64, NB - box0);
        const size_t rowbase = (size_t)r * NB;
        const float* __restrict__ src = conf + (rowbase + box0) * (size_t)NC;
        const v4f* __restrict__ s4 = (const v4f*)src;   // 16-B aligned: (8732*84)%16==0, (64*84)%16==0
        v4f* x4 = &xb4[w][0];

        // side loads issued early (NT), in flight during the conf staging
        int l = 0;
        v4f lp = {0.f, 0.f, 0.f, 0.f}, lt = {0.f, 0.f, 0.f, 0.f};
        if (ln < cnt) {
            const size_t box = rowbase + box0 + ln;
            l = __builtin_nontemporal_load(lab + box);
            lp = __builtin_nontemporal_load((const v4f*)(locp + box * 4));
            lt = __builtin_nontemporal_load((const v4f*)(loct + box * 4));
        }

        if (cnt == 64) {
            // 1344 floats = 336 vec4 = 5 full rounds of 64 + 16 leftover
            v4f t0 = __builtin_nontemporal_load(s4 + ln);
            v4f t1 = __builtin_nontemporal_load(s4 + 64 + ln);
            v4f t2 = __builtin_nontemporal_load(s4 + 128 + ln);
            v4f t3 = __builtin_nontemporal_load(s4 + 192 + ln);
            v4f t4 = __builtin_nontemporal_load(s4 + 256 + ln);
            v4f t5 = {0.f, 0.f, 0.f, 0.f};
            if (ln < 16) t5 = __builtin_nontemporal_load(s4 + 320 + ln);
            x4[ln] = t0;
            x4[64 + ln] = t1;
            x4[128 + ln] = t2;
            x4[192 + ln] = t3;
            x4[256 + ln] = t4;
            if (ln < 16) x4[320 + ln] = t5;
        } else {
            // only tail is cnt=28: 588 floats = exactly 147 vec4
            const int n4 = (cnt * NC) >> 2;
#pragma unroll
            for (int k = 0; k < 6; k++) {
                const int i4 = (k << 6) + ln;
                if (i4 < n4) x4[i4] = __builtin_nontemporal_load(s4 + i4);
            }
        }
        // wave-local cross-lane LDS dependency: drain DS queue, no barrier
        asm volatile("s_waitcnt lgkmcnt(0)" ::: "memory");

        if (ln < cnt) {
            float c[NC];
            const float* bp = (const float*)&xb4[w][0] + NC * ln;
#pragma unroll
            for (int j = 0; j < NC; j++) c[j] = bp[j];
            float m = c[0];
#pragma unroll
            for (int j = 1; j < NC; j++) m = fmaxf(m, c[j]);
            float s = 0.f;
#pragma unroll
            for (int j = 0; j < NC; j++) s += __expf(c[j] - m);
            float gold = c[0];
#pragma unroll
            for (int j = 1; j < NC; j++) gold = (j == l) ? c[j] : gold;
            const float ce = m + __logf(s) - gold;
            ceS = ce;
            if (l > 0) {
                npS = 1.f;
                pceS = ce;
                float d, ad;
                d = lp.x - lt.x; ad = fabsf(d); llS += (ad < 1.f) ? 0.5f * d * d : ad - 0.5f;
                d = lp.y - lt.y; ad = fabsf(d); llS += (ad < 1.f) ? 0.5f * d * d : ad - 0.5f;
                d = lp.z - lt.z; ad = fabsf(d); llS += (ad < 1.f) ? 0.5f * d * d : ad - 0.5f;
                d = lp.w - lt.w; ad = fabsf(d); llS += (ad < 1.f) ? 0.5f * d * d : ad - 0.5f;
            }
        }
    }

    __shared__ float sr[4][4];
    float v0 = wred_f(ceS), v1 = wred_f(pceS), v2 = wred_f(llS), v3 = wred_f(npS);
    if (ln == 0) { sr[0][w] = v0; sr[1][w] = v1; sr[2][w] = v2; sr[3][w] = v3; }
    __syncthreads();
    if (threadIdx.x == 0) {
        float A = 0, B = 0, C = 0, D = 0;
#pragma unroll
        for (int k = 0; k < 4; k++) { A += sr[0][k]; B += sr[1][k]; C += sr[2][k]; D += sr[3][k]; }
        float* slot = ws + ((size_t)r * BX + blockIdx.x) * 4;
        slot[0] = A; slot[1] = B; slot[2] = C; slot[3] = D;   // plain stores, zero contention
    }
}

__device__ inline float ce_for_box0(const float* __restrict__ cp) {
    float c[NC];
#pragma unroll
    for (int j = 0; j < NC; j++) c[j] = cp[j];
    float m = c[0];
#pragma unroll
    for (int j = 1; j < NC; j++) m = fmaxf(m, c[j]);
    float s = 0.f;
#pragma unroll
    for (int j = 0; j < NC; j++) s += __expf(c[j] - m);
    return m + __logf(s) - c[0];
}

// Block r: reduce 35 partial slots -> row sums; mining decision.
// Hot path (K >= #neg, always true on this data): conf_row = row_ce, no sort.
// Cold path: exact top-K radix select (tie values identical -> sum exact).
__global__ void __launch_bounds__(256)
kB(const float* __restrict__ conf, const int* __restrict__ lab,
   float* __restrict__ ws) {
    const int r = blockIdx.x;
    __shared__ float srow[4];
    if (threadIdx.x < 64) {                      // wave 0 reduces the 35 slots
        float a = 0, b = 0, c = 0, d = 0;
        if (threadIdx.x < BX) {
            const float4 p = *(const float4*)(ws + ((size_t)r * BX + threadIdx.x) * 4);
            a = p.x; b = p.y; c = p.z; d = p.w;
        }
        a = wred_f(a); b = wred_f(b); c = wred_f(c); d = wred_f(d);
        if (threadIdx.x == 0) { srow[0] = a; srow[1] = b; srow[2] = c; srow[3] = d; }
    }
    __syncthreads();
    const float row_ce = srow[0], row_pce = srow[1], row_ll = srow[2];
    const int np = (int)srow[3];
    const int K = min(3 * np, NB - 1);
    const int nneg = NB - np;

    float rowval;
    if (K >= nneg) {
        rowval = row_ce;
    } else if (K <= 0) {
        rowval = row_pce;
    } else {
        __shared__ unsigned key[NB];
        __shared__ unsigned hist[256];
        __shared__ unsigned sb[2];
        for (int i = threadIdx.x; i < NB; i += 256) {
            const size_t box = (size_t)r * NB + i;
            unsigned k = 0u;
            if (lab[box] == 0) {
                float ce = ce_for_box0(conf + box * (size_t)NC);
                k = __float_as_uint(fmaxf(ce, 0.f));
            }
            key[i] = k;
        }
        __syncthreads();
        unsigned prefix = 0;
        int Kr = K;
        for (int round = 3; round >= 0; --round) {
            const int sh = round * 8;
            const unsigned pmask = (round == 3) ? 0u : (0xFFFFFFFFu << (8 * (round + 1)));
            for (int b = threadIdx.x; b < 256; b += 256) hist[b] = 0;
            __syncthreads();
            for (int i = threadIdx.x; i < NB; i += 256) {
                const unsigned k = key[i];
                if ((k & pmask) == prefix) atomicAdd(&hist[(k >> sh) & 255u], 1u);
            }
            __syncthreads();
            if (threadIdx.x == 0) {
                unsigned cum = 0; int b = 255;
                for (; b > 0; --b) {
                    const unsigned h = hist[b];
                    if (cum + h >= (unsigned)Kr) break;
                    cum += h;
                }
                sb[0] = cum; sb[1] = (unsigned)b;
            }
            __syncthreads();
            Kr -= (int)sb[0];
            prefix |= (sb[1] << sh);
            __syncthreads();
        }
        float local = 0.f;
        for (int i = threadIdx.x; i < NB; i += 256) {
            const unsigned k = key[i];
            if (k > prefix) local += __uint_as_float(k);
        }
        __shared__ float sred[4];
        float vv = wred_f(local);
        const int ww = threadIdx.x >> 6, lnn = threadIdx.x & 63;
        if (lnn == 0) sred[ww] = vv;
        __syncthreads();
        rowval = row_pce + sred[0] + sred[1] + sred[2] + sred[3]
               + (float)Kr * __uint_as_float(prefix);
    }

    if (threadIdx.x == 0) {
        float* o = ws + WS_ROW + r * 4;
        o[0] = rowval; o[1] = row_ll; o[2] = srow[3];
    }
}

// Single block: reduce the 128 per-row results -> final scalar.
__global__ void __launch_bounds__(256)
kC(const float* __restrict__ ws, float* __restrict__ out) {
    float cf = 0.f, lc = 0.f, nm = 0.f;
    if (threadIdx.x < BATCH) {
        const float* o = ws + WS_ROW + threadIdx.x * 4;
        cf = o[0]; lc = o[1]; nm = o[2];
    }
    __shared__ float sf[4], sl[4], sn[4];
    float vc = wred_f(cf), vl = wred_f(lc), vn = wred_f(nm);
    const int w = threadIdx.x >> 6, ln = threadIdx.x & 63;
    if (ln == 0) { sf[w] = vc; sl[w] = vl; sn[w] = vn; }
    __syncthreads();
    if (threadIdx.x == 0) {
        const float CF = sf[0] + sf[1] + sf[2] + sf[3];
        const float LC = sl[0] + sl[1] + sl[2] + sl[3];
        const float NM = sn[0] + sn[1] + sn[2] + sn[3];
        out[0] = (LC + CF) / fmaxf(NM, 1.f);
    }
}

extern "C" void kernel_launch(void* const* d_in, const int* in_sizes, int n_in,
                              void* d_out, int out_size, void* d_ws, size_t ws_size,
                              hipStream_t stream) {
    const float* locp = (const float*)d_in[0];
    const float* loct = (const float*)d_in[1];
    const float* conf = (const float*)d_in[2];
    const int* lab = (const int*)d_in[3];
    float* out = (float*)d_out;
    float* ws = (float*)d_ws;

    hipLaunchKernelGGL(kA, dim3(BX, BATCH), dim3(256), 0, stream,
                       locp, loct, conf, lab, ws);
    hipLaunchKernelGGL(kB, dim3(BATCH), dim3(256), 0, stream, conf, lab, ws);
    hipLaunchKernelGGL(kC, dim3(1), dim3(256), 0, stream, ws, out);
}